// Round 10
// baseline (108.403 us; speedup 1.0000x reference)
//
#include <hip/hip_runtime.h>
#include <hip/hip_fp16.h>
#include <cstdint>
#include <cstddef>

typedef _Float16 f16;
typedef __attribute__((ext_vector_type(8))) _Float16 f16x8;
typedef __attribute__((ext_vector_type(4))) _Float16 f16x4;
typedef __attribute__((ext_vector_type(8))) short s16x8;    // 8 x bf16
typedef __attribute__((ext_vector_type(16))) float f32x16;

#define S_LEN 4096
#define D_DIM 1024
#define SOFT_C 160.0f

__device__ __forceinline__ void gld_lds16(const void* g, void* l) {
    auto gp = reinterpret_cast<const unsigned int __attribute__((address_space(1)))*>(
        reinterpret_cast<uintptr_t>(g));
    auto lp = reinterpret_cast<unsigned int __attribute__((address_space(3)))*>(
        reinterpret_cast<uintptr_t>(l));
    __builtin_amdgcn_global_load_lds(gp, lp, 16, 0, 0);
}

// float -> bf16 (round-to-nearest-even)
__device__ __forceinline__ unsigned short f2bf(float x) {
    unsigned u = __builtin_bit_cast(unsigned, x);
    u += 0x7FFFu + ((u >> 16) & 1u);
    return (unsigned short)(u >> 16);
}

#define SCHED0() __builtin_amdgcn_sched_barrier(0)
#define BAR()    __builtin_amdgcn_s_barrier()
#define LGKM0()  asm volatile("s_waitcnt lgkmcnt(0)" ::: "memory")
#define VM(n)    asm volatile("s_waitcnt vmcnt(" #n ")" ::: "memory")

// ---------------------------------------------------------------------------
// Fused prep: convert Q,K f32->f16 (blocks 0..8191); transpose V -> bf16
// ---------------------------------------------------------------------------
__global__ __launch_bounds__(256)
void prep(const float* __restrict__ Q, const float* __restrict__ K,
          const float* __restrict__ V,
          f16* __restrict__ Qh, f16* __restrict__ Kh, unsigned short* __restrict__ Vt)
{
    const int b = blockIdx.x;
    if (b < 8192) {
        int idx = b * 256 + threadIdx.x;
        const int NQ4 = S_LEN * D_DIM / 4;
        const float* src;
        f16* dst;
        int i = idx;
        if (i < NQ4) { src = Q; dst = Qh; }
        else         { src = K; dst = Kh; i -= NQ4; }
        float4 v = ((const float4*)src)[i];
        f16x4 h = {(_Float16)v.x, (_Float16)v.y, (_Float16)v.z, (_Float16)v.w};
        *(f16x4*)&dst[(size_t)i * 4] = h;
    } else {
        __shared__ float tile[32][33];
        const int bb = b - 8192;
        const int bx = bb & 31;
        const int by = bb >> 5;
        const int tx = threadIdx.x & 31;
        const int ty = threadIdx.x >> 5;
#pragma unroll
        for (int j = 0; j < 4; ++j)
            tile[ty + j * 8][tx] = V[(size_t)(by * 32 + ty + j * 8) * D_DIM + bx * 32 + tx];
        __syncthreads();
#pragma unroll
        for (int j = 0; j < 4; ++j)
            Vt[(size_t)(bx * 32 + ty + j * 8) * S_LEN + by * 32 + tx] =
                f2bf(tile[tx][ty + j * 8]);
    }
}

// ===========================================================================
// GEMM1: E = exp(Qh*Kh^T - C) -> bf16 + partial row sums.
// 256x256 tile, BK=64, R7 "bar2" schedule (2 barriers/K-tile, counted VM(4)),
// v_mfma_f32_32x32x16_f16: wave tile 128x64 = 4m x 2n frags of 32x32.
// A/B frag: elem(lane,j) = [row|col = lane&31][k = 8*(lane>>5)+j].
// C/D frag: col = lane&31, row = (reg&3)+8*(reg>>2)+4*(lane>>5).
// ===========================================================================
__global__ __launch_bounds__(512, 2)
void gemm_exp(const f16* __restrict__ A, const f16* __restrict__ B,
              unsigned short* __restrict__ C, float* __restrict__ psum,
              int lda, int ldb, int ldc, int K, int tilesN)
{
    __shared__ f16 sA[4][256 * 32];   // ring of 4 K-half slots (256 rows x 32 k)
    __shared__ f16 sB[4][256 * 32];

    const int tid = threadIdx.x;
    const int w = tid >> 6;
    const int l = tid & 63;
    const int lc = l & 31;            // row/col within 32-frag
    const int hk = l >> 5;            // k-subblock selector (0/1)
    const int wm = w >> 2;            // 0..1 (M half: 128 rows)
    const int wn = w & 3;             // 0..3 (N quarter: 64 cols)

    const int cpx = gridDim.x >> 3;
    const int bid = blockIdx.x;
    const int swz = (bid & 7) * cpx + (bid >> 3);
    const int tm = (swz / tilesN) * 256;
    const int tn = (swz % tilesN) * 256;
    const int NT = K >> 6;            // K-tiles of 64

    // element offsets within a half-slot; index [mi*2+s] / [ni*2+s]
    int offA[8], offB[4];
#pragma unroll
    for (int mi = 0; mi < 4; ++mi)
#pragma unroll
        for (int s = 0; s < 2; ++s) {
            const int row = wm * 128 + mi * 32 + lc;
            const int kb = s * 2 + hk;
            offA[mi * 2 + s] = row * 32 + (kb ^ ((row >> 1) & 3)) * 8;
        }
#pragma unroll
    for (int ni = 0; ni < 2; ++ni)
#pragma unroll
        for (int s = 0; s < 2; ++s) {
            const int row = wn * 64 + ni * 32 + lc;
            const int kb = s * 2 + hk;
            offB[ni * 2 + s] = row * 32 + (kb ^ ((row >> 1) & 3)) * 8;
        }

    // stage tile t (both K-halves) of A or B: 4 gld_lds per thread
    auto stA2 = [&](int t) {
        const int gk = t << 6;
#pragma unroll
        for (int kh = 0; kh < 2; ++kh) {
            const int slot = (2 * t + kh) & 3;
#pragma unroll
            for (int r = 0; r < 2; ++r) {
                const int sbase = r * 512 + (w << 6);
                const int s = sbase + l;
                const int row = s >> 2;
                const int pos = s & 3;
                const int kb = pos ^ ((row >> 1) & 3);
                gld_lds16(A + (size_t)(tm + row) * lda + gk + kh * 32 + kb * 8,
                          &sA[slot][sbase * 8]);
            }
        }
    };
    auto stB2 = [&](int t) {
        const int gk = t << 6;
#pragma unroll
        for (int kh = 0; kh < 2; ++kh) {
            const int slot = (2 * t + kh) & 3;
#pragma unroll
            for (int r = 0; r < 2; ++r) {
                const int sbase = r * 512 + (w << 6);
                const int s = sbase + l;
                const int row = s >> 2;
                const int pos = s & 3;
                const int kb = pos ^ ((row >> 1) & 3);
                gld_lds16(B + (size_t)(tn + row) * ldb + gk + kh * 32 + kb * 8,
                          &sB[slot][sbase * 8]);
            }
        }
    };

    f32x16 acc[4][2] = {};

    // prologue: tiles 0,1 fully staged; tile 0 drained (8 loads in flight)
    stA2(0); stB2(0);
    stA2(1); stB2(1);
    VM(8);
    BAR();

    for (int t = 0; t < NT; ++t) {
        const int s0 = (2 * t) & 3, s1 = (2 * t + 1) & 3;
        const f16* a0 = &sA[s0][0];
        const f16* a1 = &sA[s1][0];
        const f16* b0 = &sB[s0][0];
        const f16* b1 = &sB[s1][0];

        // ---------------- ph0: m-frags 0,1 x full K ----------------
        SCHED0();
        f16x8 af[2][4], bf[2][4];
#pragma unroll
        for (int q = 0; q < 4; ++q) af[0][q] = *(const f16x8*)(a0 + offA[q]);
#pragma unroll
        for (int q = 0; q < 4; ++q) af[1][q] = *(const f16x8*)(a1 + offA[q]);
#pragma unroll
        for (int q = 0; q < 4; ++q) bf[0][q] = *(const f16x8*)(b0 + offB[q]);
#pragma unroll
        for (int q = 0; q < 4; ++q) bf[1][q] = *(const f16x8*)(b1 + offB[q]);
        BAR(); LGKM0(); SCHED0();
        if (t + 2 < NT) stB2(t + 2);       // B slots of tile t freed by this BAR
        __builtin_amdgcn_s_setprio(1);
#pragma unroll
        for (int kh = 0; kh < 2; ++kh)
#pragma unroll
            for (int s = 0; s < 2; ++s)
#pragma unroll
                for (int mi = 0; mi < 2; ++mi)
#pragma unroll
                    for (int ni = 0; ni < 2; ++ni)
                        acc[mi][ni] = __builtin_amdgcn_mfma_f32_32x32x16_f16(
                            af[kh][mi * 2 + s], bf[kh][ni * 2 + s], acc[mi][ni], 0, 0, 0);
        __builtin_amdgcn_s_setprio(0);

        // ---------------- ph1: m-frags 2,3 x full K ----------------
        SCHED0();
        f16x8 ag[2][4];
#pragma unroll
        for (int q = 0; q < 4; ++q) ag[0][q] = *(const f16x8*)(a0 + offA[4 + q]);
#pragma unroll
        for (int q = 0; q < 4; ++q) ag[1][q] = *(const f16x8*)(a1 + offA[4 + q]);
        if (t + 2 < NT)      { VM(4); }    // drain tile t+1 stages; keep B(t+2)
        else if (t + 1 < NT) { VM(0); }
        BAR(); LGKM0(); SCHED0();
        if (t + 2 < NT) stA2(t + 2);       // A slots of tile t freed by this BAR
        __builtin_amdgcn_s_setprio(1);
#pragma unroll
        for (int kh = 0; kh < 2; ++kh)
#pragma unroll
            for (int s = 0; s < 2; ++s)
#pragma unroll
                for (int mi = 0; mi < 2; ++mi)
#pragma unroll
                    for (int ni = 0; ni < 2; ++ni)
                        acc[2 + mi][ni] = __builtin_amdgcn_mfma_f32_32x32x16_f16(
                            ag[kh][mi * 2 + s], bf[kh][ni * 2 + s], acc[2 + mi][ni], 0, 0, 0);
        __builtin_amdgcn_s_setprio(0);
    }

    // ---- epilogue: E = exp(s - C) -> bf16 store + partial row sums ----
    __syncthreads();                   // all K-loop LDS reads done; reuse sA
    float* lsum = (float*)&sA[0][0];   // [4 wn][256 rows]

#pragma unroll
    for (int mi = 0; mi < 4; ++mi) {
        float rs[16];
#pragma unroll
        for (int r = 0; r < 16; ++r) rs[r] = 0.f;
#pragma unroll
        for (int ni = 0; ni < 2; ++ni) {
            const int c0 = tn + wn * 64 + ni * 32 + lc;
#pragma unroll
            for (int r = 0; r < 16; ++r) {
                const int row = tm + wm * 128 + mi * 32 + (r & 3) + 8 * (r >> 2) + 4 * hk;
                float e = __expf(acc[mi][ni][r] - SOFT_C);
                C[(size_t)row * ldc + c0] = f2bf(e);
                rs[r] += e;
            }
        }
        // reduce over the 32 lanes (lc) holding different columns of same rows
#pragma unroll
        for (int m = 1; m < 32; m <<= 1)
#pragma unroll
            for (int r = 0; r < 16; ++r) rs[r] += __shfl_xor(rs[r], m, 64);
        if (lc == 0) {
#pragma unroll
            for (int r = 0; r < 16; ++r)
                lsum[wn * 256 + wm * 128 + mi * 32 + (r & 3) + 8 * (r >> 2) + 4 * hk] = rs[r];
        }
    }
    __syncthreads();
    if (tid < 256) {
        float s = (lsum[tid] + lsum[256 + tid]) + (lsum[512 + tid] + lsum[768 + tid]);
        psum[(size_t)(tn >> 8) * S_LEN + tm + tid] = s;
    }
}

// ---------------------------------------------------------------------------
// Row sums -> reciprocal
// ---------------------------------------------------------------------------
__global__ __launch_bounds__(256)
void sumrows(const float* __restrict__ ps, float* __restrict__ invR)
{
    const int r = blockIdx.x * 256 + threadIdx.x;
    float s = 0.f;
#pragma unroll
    for (int j = 0; j < 16; ++j) s += ps[(size_t)j * S_LEN + r];
    invR[r] = 1.0f / s;
}

// ===========================================================================
// GEMM2: partial(bf16) = E x Vt^T (un-normalized), split-K=4, same bar2
// schedule, v_mfma_f32_32x32x16_bf16. M=4096, N=1024, Ksub=1024. 256 blocks.
// ===========================================================================
__global__ __launch_bounds__(512, 2)
void gemm_bt(const unsigned short* __restrict__ A, const unsigned short* __restrict__ B,
             unsigned short* __restrict__ P)
{
    __shared__ unsigned short sA[4][256 * 32];
    __shared__ unsigned short sB[4][256 * 32];

    const int tid = threadIdx.x;
    const int w = tid >> 6;
    const int l = tid & 63;
    const int lc = l & 31;
    const int hk = l >> 5;
    const int wm = w >> 2;
    const int wn = w & 3;

    const int cpx = gridDim.x >> 3;
    const int bid = blockIdx.x;
    const int swz = (bid & 7) * cpx + (bid >> 3);
    const int split = swz & 3;
    const int tidx = swz >> 2;
    const int tm = (tidx >> 2) * 256;      // tilesN = 4
    const int tn = (tidx & 3) * 256;
    const int koff = split * 1024;
    unsigned short* Cp = P + (size_t)split * ((size_t)S_LEN * D_DIM);
    const int NT = 16;                      // 1024 / 64

    int offA[8], offB[4];
#pragma unroll
    for (int mi = 0; mi < 4; ++mi)
#pragma unroll
        for (int s = 0; s < 2; ++s) {
            const int row = wm * 128 + mi * 32 + lc;
            const int kb = s * 2 + hk;
            offA[mi * 2 + s] = row * 32 + (kb ^ ((row >> 1) & 3)) * 8;
        }
#pragma unroll
    for (int ni = 0; ni < 2; ++ni)
#pragma unroll
        for (int s = 0; s < 2; ++s) {
            const int row = wn * 64 + ni * 32 + lc;
            const int kb = s * 2 + hk;
            offB[ni * 2 + s] = row * 32 + (kb ^ ((row >> 1) & 3)) * 8;
        }

    auto stA2 = [&](int t) {
        const int gk = koff + (t << 6);
#pragma unroll
        for (int kh = 0; kh < 2; ++kh) {
            const int slot = (2 * t + kh) & 3;
#pragma unroll
            for (int r = 0; r < 2; ++r) {
                const int sbase = r * 512 + (w << 6);
                const int s = sbase + l;
                const int row = s >> 2;
                const int pos = s & 3;
                const int kb = pos ^ ((row >> 1) & 3);
                gld_lds16(A + (size_t)(tm + row) * S_LEN + gk + kh * 32 + kb * 8,
                          &sA[slot][sbase * 8]);
            }
        }
    };
    auto stB2 = [&](int t) {
        const int gk = koff + (t << 6);
#pragma unroll
        for (int kh = 0; kh < 2; ++kh) {
            const int slot = (2 * t + kh) & 3;
#pragma unroll
            for (int r = 0; r < 2; ++r) {
                const int sbase = r * 512 + (w << 6);
                const int s = sbase + l;
                const int row = s >> 2;
                const int pos = s & 3;
                const int kb = pos ^ ((row >> 1) & 3);
                gld_lds16(B + (size_t)(tn + row) * S_LEN + gk + kh * 32 + kb * 8,
                          &sB[slot][sbase * 8]);
            }
        }
    };

    f32x16 acc[4][2] = {};

    stA2(0); stB2(0);
    stA2(1); stB2(1);
    VM(8);
    BAR();

    for (int t = 0; t < NT; ++t) {
        const int s0 = (2 * t) & 3, s1 = (2 * t + 1) & 3;
        const unsigned short* a0 = &sA[s0][0];
        const unsigned short* a1 = &sA[s1][0];
        const unsigned short* b0 = &sB[s0][0];
        const unsigned short* b1 = &sB[s1][0];

        // ---------------- ph0 ----------------
        SCHED0();
        s16x8 af[2][4], bf[2][4];
#pragma unroll
        for (int q = 0; q < 4; ++q) af[0][q] = *(const s16x8*)(a0 + offA[q]);
#pragma unroll
        for (int q = 0; q < 4; ++q) af[1][q] = *(const s16x8*)(a1 + offA[q]);
#pragma unroll
        for (int q = 0; q < 4; ++q) bf[0][q] = *(const s16x8*)(b0 + offB[q]);
#pragma unroll
        for (int q = 0; q < 4; ++q) bf[1][q] = *(const s16x8*)(b1 + offB[q]);
        BAR(); LGKM0(); SCHED0();
        if (t + 2 < NT) stB2(t + 2);
        __builtin_amdgcn_s_setprio(1);
#pragma unroll
        for (int kh = 0; kh < 2; ++kh)
#pragma unroll
            for (int s = 0; s < 2; ++s)
#pragma unroll
                for (int mi = 0; mi < 2; ++mi)
#pragma unroll
                    for (int ni = 0; ni < 2; ++ni)
                        acc[mi][ni] = __builtin_amdgcn_mfma_f32_32x32x16_bf16(
                            af[kh][mi * 2 + s], bf[kh][ni * 2 + s], acc[mi][ni], 0, 0, 0);
        __builtin_amdgcn_s_setprio(0);

        // ---------------- ph1 ----------------
        SCHED0();
        s16x8 ag[2][4];
#pragma unroll
        for (int q = 0; q < 4; ++q) ag[0][q] = *(const s16x8*)(a0 + offA[4 + q]);
#pragma unroll
        for (int q = 0; q < 4; ++q) ag[1][q] = *(const s16x8*)(a1 + offA[4 + q]);
        if (t + 2 < NT)      { VM(4); }
        else if (t + 1 < NT) { VM(0); }
        BAR(); LGKM0(); SCHED0();
        if (t + 2 < NT) stA2(t + 2);
        __builtin_amdgcn_s_setprio(1);
#pragma unroll
        for (int kh = 0; kh < 2; ++kh)
#pragma unroll
            for (int s = 0; s < 2; ++s)
#pragma unroll
                for (int mi = 0; mi < 2; ++mi)
#pragma unroll
                    for (int ni = 0; ni < 2; ++ni)
                        acc[2 + mi][ni] = __builtin_amdgcn_mfma_f32_32x32x16_bf16(
                            ag[kh][mi * 2 + s], bf[kh][ni * 2 + s], acc[2 + mi][ni], 0, 0, 0);
        __builtin_amdgcn_s_setprio(0);
    }

    // epilogue: bf16 partial store (32x32 C/D layout)
#pragma unroll
    for (int mi = 0; mi < 4; ++mi)
#pragma unroll
        for (int ni = 0; ni < 2; ++ni) {
            const int c0 = tn + wn * 64 + ni * 32 + lc;
#pragma unroll
            for (int r = 0; r < 16; ++r) {
                const int row = tm + wm * 128 + mi * 32 + (r & 3) + 8 * (r >> 2) + 4 * hk;
                Cp[(size_t)row * D_DIM + c0] = f2bf(acc[mi][ni][r]);
            }
        }
}

// ---------------------------------------------------------------------------
// Combine 4 bf16 split-K partials, normalize by invR -> O f32
// ---------------------------------------------------------------------------
__global__ __launch_bounds__(256)
void combine4(const unsigned short* __restrict__ P, const float* __restrict__ invR,
              float* __restrict__ O)
{
    const size_t g = (size_t)blockIdx.x * 256 + threadIdx.x;
    const size_t n = (size_t)S_LEN * D_DIM;
    const int row = (int)(g >> 8);
    const float s = invR[row];
    float4 r = {0.f, 0.f, 0.f, 0.f};
#pragma unroll
    for (int sp = 0; sp < 4; ++sp) {
        uint2 u = ((const uint2*)(P + (size_t)sp * n))[g];
        r.x += __builtin_bit_cast(float, (u.x & 0xFFFFu) << 16);
        r.y += __builtin_bit_cast(float, u.x & 0xFFFF0000u);
        r.z += __builtin_bit_cast(float, (u.y & 0xFFFFu) << 16);
        r.w += __builtin_bit_cast(float, u.y & 0xFFFF0000u);
    }
    r.x *= s; r.y *= s; r.z *= s; r.w *= s;
    ((float4*)O)[g] = r;
}

// ---------------------------------------------------------------------------
// Fallback: naive 2-pass attention
// ---------------------------------------------------------------------------
__global__ __launch_bounds__(256)
void attn_naive(const float* __restrict__ Q, const float* __restrict__ K,
                const float* __restrict__ V, float* __restrict__ O)
{
    const int r = blockIdx.x;
    const int t = threadIdx.x;
    __shared__ float red[4];
    float q[4];
#pragma unroll
    for (int i = 0; i < 4; ++i) q[i] = Q[(size_t)r * D_DIM + t + i * 256];

    float m = -1e30f;
    for (int j = 0; j < S_LEN; ++j) {
        float p = 0.f;
#pragma unroll
        for (int i = 0; i < 4; ++i) p += q[i] * K[(size_t)j * D_DIM + t + i * 256];
#pragma unroll
        for (int off = 32; off > 0; off >>= 1) p += __shfl_xor(p, off, 64);
        if ((t & 63) == 0) red[t >> 6] = p;
        __syncthreads();
        float s = (red[0] + red[1]) + (red[2] + red[3]);
        __syncthreads();
        m = fmaxf(m, s);
    }
    float acc[4] = {0.f, 0.f, 0.f, 0.f};
    float lsum = 0.f;
    for (int j = 0; j < S_LEN; ++j) {
        float p = 0.f;
#pragma unroll
        for (int i = 0; i < 4; ++i) p += q[i] * K[(size_t)j * D_DIM + t + i * 256];
#pragma unroll
        for (int off = 32; off > 0; off >>= 1) p += __shfl_xor(p, off, 64);
        if ((t & 63) == 0) red[t >> 6] = p;
        __syncthreads();
        float s = (red[0] + red[1]) + (red[2] + red[3]);
        __syncthreads();
        float e = __expf(s - m);
        lsum += e;
#pragma unroll
        for (int i = 0; i < 4; ++i) acc[i] += e * V[(size_t)j * D_DIM + t + i * 256];
    }
    const float inv = 1.f / lsum;
#pragma unroll
    for (int i = 0; i < 4; ++i) O[(size_t)r * D_DIM + t + i * 256] = acc[i] * inv;
}

// ---------------------------------------------------------------------------
extern "C" void kernel_launch(void* const* d_in, const int* in_sizes, int n_in,
                              void* d_out, int out_size, void* d_ws, size_t ws_size,
                              hipStream_t stream)
{
    const float* Q = (const float*)d_in[0];
    const float* K = (const float*)d_in[1];
    const float* V = (const float*)d_in[2];
    float* O = (float*)d_out;

    const size_t MB = 1024ull * 1024ull;
    const size_t QH_OFF = 0;
    const size_t KH_OFF = 8 * MB;
    const size_t VT_OFF = 16 * MB;
    const size_t E_OFF  = 24 * MB;
    const size_t PS_OFF = 56 * MB;
    const size_t IV_OFF = 56 * MB + 512 * 1024;
    const size_t P_OFF  = 57 * MB;
    const size_t NEED   = 90 * MB;

    if (ws_size < NEED) {
        attn_naive<<<S_LEN, 256, 0, stream>>>(Q, K, V, O);
        return;
    }

    char* ws = (char*)d_ws;
    f16*            Qh  = (f16*)(ws + QH_OFF);
    f16*            Kh  = (f16*)(ws + KH_OFF);
    unsigned short* Vt  = (unsigned short*)(ws + VT_OFF);
    unsigned short* E   = (unsigned short*)(ws + E_OFF);
    float*          ps  = (float*)(ws + PS_OFF);
    float*          inv = (float*)(ws + IV_OFF);
    unsigned short* P   = (unsigned short*)(ws + P_OFF);

    prep<<<8192 + 4096, 256, 0, stream>>>(Q, K, V, Qh, Kh, Vt);

    // E = exp(Qh*Kh^T - C) bf16 + partial row sums
    gemm_exp<<<256, 512, 0, stream>>>(Qh, Kh, E, ps, D_DIM, D_DIM, S_LEN,
                                      D_DIM, 16);

    sumrows<<<16, 256, 0, stream>>>(ps, inv);

    // partials = E x Vt^T (un-normalized), split-K=4
    gemm_bt<<<256, 512, 0, stream>>>(E, Vt, P);

    // O = invR * sum(partials)
    combine4<<<S_LEN * D_DIM / 4 / 256, 256, 0, stream>>>(P, inv, O);
}

// Round 11
// 94.743 us; speedup vs baseline: 1.1442x; 1.1442x over previous
//
#include <hip/hip_runtime.h>
#include <hip/hip_fp16.h>
#include <cstdint>
#include <cstddef>

typedef _Float16 f16;
typedef __attribute__((ext_vector_type(8))) _Float16 f16x8;
typedef __attribute__((ext_vector_type(4))) _Float16 f16x4;
typedef __attribute__((ext_vector_type(8))) short s16x8;   // 8 x bf16
typedef __attribute__((ext_vector_type(4))) float f32x4;

#define S_LEN 4096
#define D_DIM 1024
#define SOFT_C 160.0f

__device__ __forceinline__ void gld_lds16(const void* g, void* l) {
    auto gp = reinterpret_cast<const unsigned int __attribute__((address_space(1)))*>(
        reinterpret_cast<uintptr_t>(g));
    auto lp = reinterpret_cast<unsigned int __attribute__((address_space(3)))*>(
        reinterpret_cast<uintptr_t>(l));
    __builtin_amdgcn_global_load_lds(gp, lp, 16, 0, 0);
}

// float -> bf16 (round-to-nearest-even)
__device__ __forceinline__ unsigned short f2bf(float x) {
    unsigned u = __builtin_bit_cast(unsigned, x);
    u += 0x7FFFu + ((u >> 16) & 1u);
    return (unsigned short)(u >> 16);
}

#define SCHED0() __builtin_amdgcn_sched_barrier(0)
#define BAR()    __builtin_amdgcn_s_barrier()
#define LGKM0()  asm volatile("s_waitcnt lgkmcnt(0)" ::: "memory")
#define VM(n)    asm volatile("s_waitcnt vmcnt(" #n ")" ::: "memory")

// ---------------------------------------------------------------------------
// Fused prep: convert Q,K f32->f16 (blocks 0..8191); transpose V -> bf16
// ---------------------------------------------------------------------------
__global__ __launch_bounds__(256)
void prep(const float* __restrict__ Q, const float* __restrict__ K,
          const float* __restrict__ V,
          f16* __restrict__ Qh, f16* __restrict__ Kh, unsigned short* __restrict__ Vt)
{
    const int b = blockIdx.x;
    if (b < 8192) {
        int idx = b * 256 + threadIdx.x;
        const int NQ4 = S_LEN * D_DIM / 4;
        const float* src;
        f16* dst;
        int i = idx;
        if (i < NQ4) { src = Q; dst = Qh; }
        else         { src = K; dst = Kh; i -= NQ4; }
        float4 v = ((const float4*)src)[i];
        f16x4 h = {(_Float16)v.x, (_Float16)v.y, (_Float16)v.z, (_Float16)v.w};
        *(f16x4*)&dst[(size_t)i * 4] = h;
    } else {
        __shared__ float tile[32][33];
        const int bb = b - 8192;
        const int bx = bb & 31;
        const int by = bb >> 5;
        const int tx = threadIdx.x & 31;
        const int ty = threadIdx.x >> 5;
#pragma unroll
        for (int j = 0; j < 4; ++j)
            tile[ty + j * 8][tx] = V[(size_t)(by * 32 + ty + j * 8) * D_DIM + bx * 32 + tx];
        __syncthreads();
#pragma unroll
        for (int j = 0; j < 4; ++j)
            Vt[(size_t)(bx * 32 + ty + j * 8) * S_LEN + by * 32 + tx] =
                f2bf(tile[tx][ty + j * 8]);
    }
}

// ===========================================================================
// GEMM1: E = exp(Qh*Kh^T - C) -> bf16 + partial row sums.
// 256x256 tile, BK=64, "bar2" schedule (R7-proven): 2 barriers / K-tile.
//   ph0: read af(mh0,k0|k1)+bf(k0|k1) -> BAR -> lgkm0 -> stage B(t+2) -> 32 MFMA
//   ph1: read ag(mh1,k0|k1) -> vmcnt(4) -> BAR -> lgkm0 -> stage A(t+2) -> 32 MFMA
// vmcnt(4) pre-barrier: each wave drains its own A(t+1)/B(t+1) stage loads
// before the barrier that precedes cross-wave reads of those slots.
// ===========================================================================
__global__ __launch_bounds__(512, 2)
void gemm_exp(const f16* __restrict__ A, const f16* __restrict__ B,
              unsigned short* __restrict__ C, float* __restrict__ psum,
              int lda, int ldb, int ldc, int K, int tilesN)
{
    __shared__ f16 sA[4][256 * 32];   // ring of 4 K-half slots (256 rows x 32 k)
    __shared__ f16 sB[4][256 * 32];

    const int tid = threadIdx.x;
    const int w = tid >> 6;
    const int l = tid & 63;
    const int lr = l & 15;
    const int lk = l >> 4;
    const int wm = w >> 2;
    const int wn = w & 3;

    const int cpx = gridDim.x >> 3;
    const int bid = blockIdx.x;
    const int swz = (bid & 7) * cpx + (bid >> 3);
    const int tm = (swz / tilesN) * 256;
    const int tn = (swz % tilesN) * 256;
    const int NT = K >> 6;            // K-tiles of 64

    int offA[8], offB[4];
#pragma unroll
    for (int mi = 0; mi < 8; ++mi) {
        const int ra = wm * 128 + mi * 16 + lr;
        offA[mi] = ra * 32 + (lk ^ ((ra >> 1) & 3)) * 8;
    }
#pragma unroll
    for (int ni = 0; ni < 4; ++ni) {
        const int rb = wn * 64 + ni * 16 + lr;
        offB[ni] = rb * 32 + (lk ^ ((rb >> 1) & 3)) * 8;
    }

    // stage tile t (both K-halves) of A or B: 4 gld_lds per thread
    auto stA2 = [&](int t) {
        const int gk = t << 6;
#pragma unroll
        for (int kh = 0; kh < 2; ++kh) {
            const int slot = (2 * t + kh) & 3;
#pragma unroll
            for (int r = 0; r < 2; ++r) {
                const int sbase = r * 512 + (w << 6);
                const int s = sbase + l;
                const int row = s >> 2;
                const int pos = s & 3;
                const int kb = pos ^ ((row >> 1) & 3);
                gld_lds16(A + (size_t)(tm + row) * lda + gk + kh * 32 + kb * 8,
                          &sA[slot][sbase * 8]);
            }
        }
    };
    auto stB2 = [&](int t) {
        const int gk = t << 6;
#pragma unroll
        for (int kh = 0; kh < 2; ++kh) {
            const int slot = (2 * t + kh) & 3;
#pragma unroll
            for (int r = 0; r < 2; ++r) {
                const int sbase = r * 512 + (w << 6);
                const int s = sbase + l;
                const int row = s >> 2;
                const int pos = s & 3;
                const int kb = pos ^ ((row >> 1) & 3);
                gld_lds16(B + (size_t)(tn + row) * ldb + gk + kh * 32 + kb * 8,
                          &sB[slot][sbase * 8]);
            }
        }
    };

    f32x4 acc[8][4] = {};
    f16x8 af[2][4], bf[2][4], ag[2][4];

    // prologue: tiles 0,1 fully staged; tile 0 drained (A(1),B(1)=8 in flight)
    stA2(0); stB2(0);
    stA2(1); stB2(1);
    VM(8);
    BAR();

    for (int t = 0; t < NT; ++t) {
        const int s0 = (2 * t) & 3, s1 = (2 * t + 1) & 3;

        // ---------------- ph0: m-half 0, full K ----------------
        SCHED0();
#pragma unroll
        for (int i = 0; i < 4; ++i) af[0][i] = *(const f16x8*)(&sA[s0][0] + offA[i]);
#pragma unroll
        for (int i = 0; i < 4; ++i) af[1][i] = *(const f16x8*)(&sA[s1][0] + offA[i]);
#pragma unroll
        for (int i = 0; i < 4; ++i) bf[0][i] = *(const f16x8*)(&sB[s0][0] + offB[i]);
#pragma unroll
        for (int i = 0; i < 4; ++i) bf[1][i] = *(const f16x8*)(&sB[s1][0] + offB[i]);
        BAR(); LGKM0(); SCHED0();
        if (t + 2 < NT) stB2(t + 2);       // B slots of tile t freed by this BAR
        __builtin_amdgcn_s_setprio(1);
#pragma unroll
        for (int kh = 0; kh < 2; ++kh)
#pragma unroll
            for (int mi = 0; mi < 4; ++mi)
#pragma unroll
                for (int ni = 0; ni < 4; ++ni)
                    acc[mi][ni] = __builtin_amdgcn_mfma_f32_16x16x32_f16(
                        af[kh][mi], bf[kh][ni], acc[mi][ni], 0, 0, 0);
        __builtin_amdgcn_s_setprio(0);

        // ---------------- ph1: m-half 1, full K ----------------
        SCHED0();
#pragma unroll
        for (int i = 0; i < 4; ++i) ag[0][i] = *(const f16x8*)(&sA[s0][0] + offA[4 + i]);
#pragma unroll
        for (int i = 0; i < 4; ++i) ag[1][i] = *(const f16x8*)(&sA[s1][0] + offA[4 + i]);
        // drain own stage loads for tile t+1 (keep B(t+2)'s 4 in flight)
        if (t + 2 < NT)      { VM(4); }
        else if (t + 1 < NT) { VM(0); }
        BAR(); LGKM0(); SCHED0();
        if (t + 2 < NT) stA2(t + 2);       // A slots of tile t freed by this BAR
        __builtin_amdgcn_s_setprio(1);
#pragma unroll
        for (int kh = 0; kh < 2; ++kh)
#pragma unroll
            for (int mi = 0; mi < 4; ++mi)
#pragma unroll
                for (int ni = 0; ni < 4; ++ni)
                    acc[4 + mi][ni] = __builtin_amdgcn_mfma_f32_16x16x32_f16(
                        ag[kh][mi], bf[kh][ni], acc[4 + mi][ni], 0, 0, 0);
        __builtin_amdgcn_s_setprio(0);
    }

    // ---- epilogue: E = exp(s - C) -> bf16 store + partial row sums ----
    float rs[8][4];
#pragma unroll
    for (int mi = 0; mi < 8; ++mi)
#pragma unroll
        for (int j = 0; j < 4; ++j) rs[mi][j] = 0.f;

#pragma unroll
    for (int mi = 0; mi < 8; ++mi) {
        const int r0 = tm + wm * 128 + mi * 16 + (l >> 4) * 4;
#pragma unroll
        for (int ni = 0; ni < 4; ++ni) {
            const int c0 = tn + wn * 64 + ni * 16 + lr;
#pragma unroll
            for (int j = 0; j < 4; ++j) {
                float e = __expf(acc[mi][ni][j] - SOFT_C);
                C[(size_t)(r0 + j) * ldc + c0] = f2bf(e);
                rs[mi][j] += e;
            }
        }
    }
#pragma unroll
    for (int mi = 0; mi < 8; ++mi)
#pragma unroll
        for (int j = 0; j < 4; ++j)
#pragma unroll
            for (int m = 1; m < 16; m <<= 1)
                rs[mi][j] += __shfl_xor(rs[mi][j], m, 64);

    float* lsum = (float*)&sA[0][0];   // [4 wn][256 rows]
    __syncthreads();
    if (lr == 0) {
#pragma unroll
        for (int mi = 0; mi < 8; ++mi)
#pragma unroll
            for (int j = 0; j < 4; ++j)
                lsum[wn * 256 + wm * 128 + mi * 16 + (l >> 4) * 4 + j] = rs[mi][j];
    }
    __syncthreads();
    if (tid < 256) {
        float s = (lsum[tid] + lsum[256 + tid]) + (lsum[512 + tid] + lsum[768 + tid]);
        psum[(size_t)(tn >> 8) * S_LEN + tm + tid] = s;
    }
}

// ===========================================================================
// GEMM2: partial(bf16) = E x Vt^T (un-normalized), split-K=4, same "bar2"
// schedule, bf16 MFMA. M=4096, N=1024, Ksub=1024. 256 blocks.
// ===========================================================================
__global__ __launch_bounds__(512, 2)
void gemm_bt(const unsigned short* __restrict__ A, const unsigned short* __restrict__ B,
             unsigned short* __restrict__ P)
{
    __shared__ unsigned short sA[4][256 * 32];
    __shared__ unsigned short sB[4][256 * 32];

    const int tid = threadIdx.x;
    const int w = tid >> 6;
    const int l = tid & 63;
    const int lr = l & 15;
    const int lk = l >> 4;
    const int wm = w >> 2;
    const int wn = w & 3;

    const int cpx = gridDim.x >> 3;
    const int bid = blockIdx.x;
    const int swz = (bid & 7) * cpx + (bid >> 3);
    const int split = swz & 3;
    const int tidx = swz >> 2;
    const int tm = (tidx >> 2) * 256;      // tilesN = 4
    const int tn = (tidx & 3) * 256;
    const int koff = split * 1024;
    unsigned short* Cp = P + (size_t)split * ((size_t)S_LEN * D_DIM);
    const int NT = 16;                      // 1024 / 64

    int offA[8], offB[4];
#pragma unroll
    for (int mi = 0; mi < 8; ++mi) {
        const int ra = wm * 128 + mi * 16 + lr;
        offA[mi] = ra * 32 + (lk ^ ((ra >> 1) & 3)) * 8;
    }
#pragma unroll
    for (int ni = 0; ni < 4; ++ni) {
        const int rb = wn * 64 + ni * 16 + lr;
        offB[ni] = rb * 32 + (lk ^ ((rb >> 1) & 3)) * 8;
    }

    auto stA2 = [&](int t) {
        const int gk = koff + (t << 6);
#pragma unroll
        for (int kh = 0; kh < 2; ++kh) {
            const int slot = (2 * t + kh) & 3;
#pragma unroll
            for (int r = 0; r < 2; ++r) {
                const int sbase = r * 512 + (w << 6);
                const int s = sbase + l;
                const int row = s >> 2;
                const int pos = s & 3;
                const int kb = pos ^ ((row >> 1) & 3);
                gld_lds16(A + (size_t)(tm + row) * S_LEN + gk + kh * 32 + kb * 8,
                          &sA[slot][sbase * 8]);
            }
        }
    };
    auto stB2 = [&](int t) {
        const int gk = koff + (t << 6);
#pragma unroll
        for (int kh = 0; kh < 2; ++kh) {
            const int slot = (2 * t + kh) & 3;
#pragma unroll
            for (int r = 0; r < 2; ++r) {
                const int sbase = r * 512 + (w << 6);
                const int s = sbase + l;
                const int row = s >> 2;
                const int pos = s & 3;
                const int kb = pos ^ ((row >> 1) & 3);
                gld_lds16(B + (size_t)(tn + row) * S_LEN + gk + kh * 32 + kb * 8,
                          &sB[slot][sbase * 8]);
            }
        }
    };

    f32x4 acc[8][4] = {};
    s16x8 af[2][4], bf[2][4], ag[2][4];

    stA2(0); stB2(0);
    stA2(1); stB2(1);
    VM(8);
    BAR();

    for (int t = 0; t < NT; ++t) {
        const int s0 = (2 * t) & 3, s1 = (2 * t + 1) & 3;

        // ---------------- ph0 ----------------
        SCHED0();
#pragma unroll
        for (int i = 0; i < 4; ++i) af[0][i] = *(const s16x8*)(&sA[s0][0] + offA[i]);
#pragma unroll
        for (int i = 0; i < 4; ++i) af[1][i] = *(const s16x8*)(&sA[s1][0] + offA[i]);
#pragma unroll
        for (int i = 0; i < 4; ++i) bf[0][i] = *(const s16x8*)(&sB[s0][0] + offB[i]);
#pragma unroll
        for (int i = 0; i < 4; ++i) bf[1][i] = *(const s16x8*)(&sB[s1][0] + offB[i]);
        BAR(); LGKM0(); SCHED0();
        if (t + 2 < NT) stB2(t + 2);
        __builtin_amdgcn_s_setprio(1);
#pragma unroll
        for (int kh = 0; kh < 2; ++kh)
#pragma unroll
            for (int mi = 0; mi < 4; ++mi)
#pragma unroll
                for (int ni = 0; ni < 4; ++ni)
                    acc[mi][ni] = __builtin_amdgcn_mfma_f32_16x16x32_bf16(
                        af[kh][mi], bf[kh][ni], acc[mi][ni], 0, 0, 0);
        __builtin_amdgcn_s_setprio(0);

        // ---------------- ph1 ----------------
        SCHED0();
#pragma unroll
        for (int i = 0; i < 4; ++i) ag[0][i] = *(const s16x8*)(&sA[s0][0] + offA[4 + i]);
#pragma unroll
        for (int i = 0; i < 4; ++i) ag[1][i] = *(const s16x8*)(&sA[s1][0] + offA[4 + i]);
        if (t + 2 < NT)      { VM(4); }
        else if (t + 1 < NT) { VM(0); }
        BAR(); LGKM0(); SCHED0();
        if (t + 2 < NT) stA2(t + 2);
        __builtin_amdgcn_s_setprio(1);
#pragma unroll
        for (int kh = 0; kh < 2; ++kh)
#pragma unroll
            for (int mi = 0; mi < 4; ++mi)
#pragma unroll
                for (int ni = 0; ni < 4; ++ni)
                    acc[4 + mi][ni] = __builtin_amdgcn_mfma_f32_16x16x32_bf16(
                        ag[kh][mi], bf[kh][ni], acc[4 + mi][ni], 0, 0, 0);
        __builtin_amdgcn_s_setprio(0);
    }

    // epilogue: bf16 partial store
#pragma unroll
    for (int mi = 0; mi < 8; ++mi) {
        const int r0 = tm + wm * 128 + mi * 16 + (l >> 4) * 4;
#pragma unroll
        for (int ni = 0; ni < 4; ++ni) {
            const int c0 = tn + wn * 64 + ni * 16 + lr;
#pragma unroll
            for (int j = 0; j < 4; ++j)
                Cp[(size_t)(r0 + j) * D_DIM + c0] = f2bf(acc[mi][ni][j]);
        }
    }
}

// ---------------------------------------------------------------------------
// Combine 4 bf16 split-K partials + inline row-sum normalize -> O f32.
// One block per row (1024 cols = 256 thr x 4): inv computed from the 16
// psum partials via LDS broadcast (replaces the separate sumrows kernel).
// ---------------------------------------------------------------------------
__global__ __launch_bounds__(256)
void combine4(const unsigned short* __restrict__ P, const float* __restrict__ ps,
              float* __restrict__ O)
{
    const int row = blockIdx.x;
    const int tid = threadIdx.x;
    __shared__ float sh[16];
    if (tid < 16) sh[tid] = ps[(size_t)tid * S_LEN + row];
    __syncthreads();
    float s = 0.f;
#pragma unroll
    for (int j = 0; j < 16; ++j) s += sh[j];
    const float inv = 1.0f / s;

    const size_t g = (size_t)row * 256 + tid;
    const size_t n = (size_t)S_LEN * D_DIM;
    float4 r = {0.f, 0.f, 0.f, 0.f};
#pragma unroll
    for (int sp = 0; sp < 4; ++sp) {
        uint2 u = ((const uint2*)(P + (size_t)sp * n))[g];
        r.x += __builtin_bit_cast(float, (u.x & 0xFFFFu) << 16);
        r.y += __builtin_bit_cast(float, u.x & 0xFFFF0000u);
        r.z += __builtin_bit_cast(float, (u.y & 0xFFFFu) << 16);
        r.w += __builtin_bit_cast(float, u.y & 0xFFFF0000u);
    }
    r.x *= inv; r.y *= inv; r.z *= inv; r.w *= inv;
    ((float4*)O)[g] = r;
}

// ---------------------------------------------------------------------------
// Fallback: naive 2-pass attention
// ---------------------------------------------------------------------------
__global__ __launch_bounds__(256)
void attn_naive(const float* __restrict__ Q, const float* __restrict__ K,
                const float* __restrict__ V, float* __restrict__ O)
{
    const int r = blockIdx.x;
    const int t = threadIdx.x;
    __shared__ float red[4];
    float q[4];
#pragma unroll
    for (int i = 0; i < 4; ++i) q[i] = Q[(size_t)r * D_DIM + t + i * 256];

    float m = -1e30f;
    for (int j = 0; j < S_LEN; ++j) {
        float p = 0.f;
#pragma unroll
        for (int i = 0; i < 4; ++i) p += q[i] * K[(size_t)j * D_DIM + t + i * 256];
#pragma unroll
        for (int off = 32; off > 0; off >>= 1) p += __shfl_xor(p, off, 64);
        if ((t & 63) == 0) red[t >> 6] = p;
        __syncthreads();
        float s = (red[0] + red[1]) + (red[2] + red[3]);
        __syncthreads();
        m = fmaxf(m, s);
    }
    float acc[4] = {0.f, 0.f, 0.f, 0.f};
    float lsum = 0.f;
    for (int j = 0; j < S_LEN; ++j) {
        float p = 0.f;
#pragma unroll
        for (int i = 0; i < 4; ++i) p += q[i] * K[(size_t)j * D_DIM + t + i * 256];
#pragma unroll
        for (int off = 32; off > 0; off >>= 1) p += __shfl_xor(p, off, 64);
        if ((t & 63) == 0) red[t >> 6] = p;
        __syncthreads();
        float s = (red[0] + red[1]) + (red[2] + red[3]);
        __syncthreads();
        float e = __expf(s - m);
        lsum += e;
#pragma unroll
        for (int i = 0; i < 4; ++i) acc[i] += e * V[(size_t)j * D_DIM + t + i * 256];
    }
    const float inv = 1.f / lsum;
#pragma unroll
    for (int i = 0; i < 4; ++i) O[(size_t)r * D_DIM + t + i * 256] = acc[i] * inv;
}

// ---------------------------------------------------------------------------
extern "C" void kernel_launch(void* const* d_in, const int* in_sizes, int n_in,
                              void* d_out, int out_size, void* d_ws, size_t ws_size,
                              hipStream_t stream)
{
    const float* Q = (const float*)d_in[0];
    const float* K = (const float*)d_in[1];
    const float* V = (const float*)d_in[2];
    float* O = (float*)d_out;

    const size_t MB = 1024ull * 1024ull;
    const size_t QH_OFF = 0;
    const size_t KH_OFF = 8 * MB;
    const size_t VT_OFF = 16 * MB;
    const size_t E_OFF  = 24 * MB;
    const size_t PS_OFF = 56 * MB;                 // [16][4096] f32 = 256 KB
    const size_t P_OFF  = 57 * MB;
    const size_t NEED   = 90 * MB;

    if (ws_size < NEED) {
        attn_naive<<<S_LEN, 256, 0, stream>>>(Q, K, V, O);
        return;
    }

    char* ws = (char*)d_ws;
    f16*            Qh  = (f16*)(ws + QH_OFF);
    f16*            Kh  = (f16*)(ws + KH_OFF);
    unsigned short* Vt  = (unsigned short*)(ws + VT_OFF);
    unsigned short* E   = (unsigned short*)(ws + E_OFF);
    float*          ps  = (float*)(ws + PS_OFF);
    unsigned short* P   = (unsigned short*)(ws + P_OFF);

    prep<<<8192 + 4096, 256, 0, stream>>>(Q, K, V, Qh, Kh, Vt);

    // E = exp(Qh*Kh^T - C) bf16 + partial row sums
    gemm_exp<<<256, 512, 0, stream>>>(Qh, Kh, E, ps, D_DIM, D_DIM, S_LEN,
                                      D_DIM, 16);

    // partials = E x Vt^T (un-normalized), split-K=4
    gemm_bt<<<256, 512, 0, stream>>>(E, Vt, P);

    // O = (1/rowsum) * sum(partials)  (rowsum folded in; one block per row)
    combine4<<<S_LEN, 256, 0, stream>>>(P, ps, O);
}